// Round 3
// baseline (553.953 us; speedup 1.0000x reference)
//
#include <hip/hip_runtime.h>
#include <math.h>

#define H 256
#define V 32000
#define L 2048
#define B 64
#define NCH 16          // l-chunks for flash pass (128 l each)
#define SC 32           // sub-chunk staged in LDS (32 x 256 floats = 32 KB)

// ws layout (float offsets) — no overlap, total ~1.7 MB
#define WS_W2     0                        // [H]   = (attn_W^T @ flatten)[H:2H]
#define WS_E      256                      // [B*L] energies
#define WS_CPART  (256 + B*L)              // [NCH*B*H] context partials
#define WS_MPART  (WS_CPART + NCH*B*H)     // [NCH*B] chunk max
#define WS_SPART  (WS_MPART + NCH*B)       // [NCH*B] chunk sumexp
#define WS_XCAT2  (WS_SPART + NCH*B)       // [B*2H] = [h_new ; context]

// ---------------- k1: w2[j] = sum_h attn_W[h, H+j] * flatten[h]
// (e_h and bias terms are per-row constants under softmax -> dropped)
__global__ __launch_bounds__(1024) void k1_w2(
    const float* __restrict__ attn_W, const float* __restrict__ flatten,
    float* __restrict__ ws) {
  __shared__ float fv[H];
  __shared__ float part[4][H];
  int tid = threadIdx.x;
  if (tid < H) fv[tid] = flatten[tid];
  __syncthreads();
  int j = tid & 255, g = tid >> 8;
  float acc = 0.f;
#pragma unroll 8
  for (int i = 0; i < 64; ++i) {
    int h = g * 64 + i;
    acc += attn_W[h * 2 * H + H + j] * fv[h];
  }
  part[g][j] = acc;
  __syncthreads();
  if (tid < H)
    ws[WS_W2 + tid] = part[0][tid] + part[1][tid] + part[2][tid] + part[3][tid];
}

// ---------------- kA: single pass over enc: energies + online softmax + context
// block (b, ch) handles l in [ch*128, ch*128+128); 4 sub-chunks of 32 staged in LDS.
__global__ __launch_bounds__(256) void kA_flash(
    const float* __restrict__ enc, float* __restrict__ ws) {
  int b = blockIdx.x, ch = blockIdx.y;
  int tid = threadIdx.x, lane = tid & 63, wv = tid >> 6;
  __shared__ float encS[SC * H];     // 32 KB
  __shared__ float es[SC];
  __shared__ float ps[SC];
  const float4* enc4 = (const float4*)enc;
  float4* encS4 = (float4*)encS;
  float4 w2 = ((const float4*)(ws + WS_W2))[lane];
  float m = -INFINITY, s = 0.f, c = 0.f;   // c: this thread's h = tid
  for (int sc = 0; sc < (L / NCH) / SC; ++sc) {
    int l0 = ch * (L / NCH) + sc * SC;
    __syncthreads();   // protect encS from previous iteration's readers
    // stage 32 rows (32 KB) coalesced
#pragma unroll
    for (int t = 0; t < 8; ++t) {
      int idx = tid + t * 256;           // < 2048
      int r = idx >> 6, col4 = idx & 63;
      encS4[r * 64 + col4] = enc4[((size_t)(l0 + r) * B + b) * 64 + col4];
    }
    __syncthreads();
    // energies: wave wv does l = wv*8 .. wv*8+7
#pragma unroll
    for (int i = 0; i < 8; ++i) {
      int l = wv * 8 + i;
      float4 ev = encS4[l * 64 + lane];
      float v = ev.x * w2.x + ev.y * w2.y + ev.z * w2.z + ev.w * w2.w;
      for (int off = 32; off > 0; off >>= 1) v += __shfl_xor(v, off, 64);
      if (lane == 0) {
        es[l] = v;
        ws[WS_E + (size_t)b * L + l0 + l] = v;
      }
    }
    __syncthreads();
    // online update (identical redundant compute across threads)
    float newm = m;
#pragma unroll
    for (int l = 0; l < SC; ++l) newm = fmaxf(newm, es[l]);
    if (tid < SC) ps[tid] = expf(es[tid] - newm);
    __syncthreads();
    float f = expf(m - newm);            // m=-inf first iter -> f=0, c=s=0 anyway
    float accS = 0.f;
    float cnew = c * f;
#pragma unroll
    for (int l = 0; l < SC; ++l) {
      float p = ps[l];
      accS += p;
      cnew += p * encS[l * H + tid];
    }
    c = cnew;
    s = s * f + accS;
    m = newm;
  }
  ws[WS_CPART + ((size_t)ch * B + b) * H + tid] = c;
  if (tid == 0) {
    ws[WS_MPART + ch * B + b] = m;
    ws[WS_SPART + ch * B + b] = s;
  }
}

// ---------------- kB: combine chunks -> context; attn_weights; GRU step
__global__ __launch_bounds__(768) void kB_gru(
    const int* __restrict__ input, const float* __restrict__ hidden,
    const float* __restrict__ emb, const float* __restrict__ Wih,
    const float* __restrict__ Whh, const float* __restrict__ bih,
    const float* __restrict__ bhh, float* __restrict__ ws,
    float* __restrict__ d_out) {
  int b = blockIdx.x, tid = threadIdx.x;
  __shared__ float fch[NCH];
  __shared__ float x_s[2 * H];
  __shared__ float h_s[H];
  __shared__ float gi_s[3 * H];
  __shared__ float gh_s[3 * H];
  // global max / sum (redundant per thread; uniform addresses -> scalar loads)
  float M = -INFINITY;
#pragma unroll
  for (int ch = 0; ch < NCH; ++ch) M = fmaxf(M, ws[WS_MPART + ch * B + b]);
  float S = 0.f;
#pragma unroll
  for (int ch = 0; ch < NCH; ++ch)
    S += ws[WS_SPART + ch * B + b] * expf(ws[WS_MPART + ch * B + b] - M);
  float invS = 1.f / S;
  if (tid < NCH) fch[tid] = expf(ws[WS_MPART + tid * B + b] - M);
  // attn_weights out (independent of LDS below)
  for (int l = tid; l < L; l += 768) {
    float e = ws[WS_E + (size_t)b * L + l];
    d_out[(size_t)B * V + (size_t)B * H + (size_t)b * L + l] = expf(e - M) * invS;
  }
  if (tid < H) h_s[tid] = hidden[(size_t)b * H + tid];
  __syncthreads();
  float cfin = 0.f;
  if (tid < H) {
#pragma unroll
    for (int ch = 0; ch < NCH; ++ch)
      cfin += ws[WS_CPART + ((size_t)ch * B + b) * H + tid] * fch[ch];
    cfin *= invS;
    int tok = input[b];
    x_s[tid] = emb[(size_t)tok * H + tid];
    x_s[H + tid] = cfin;
  }
  __syncthreads();
  // gi[j] = Wih[j,:] . x + bih[j]  (512) ; gh[j] = Whh[j,:] . h + bhh[j] (256)
  {
    int j = tid;
    const float4* wr = (const float4*)(Wih + (size_t)j * 2 * H);
    const float4* xr = (const float4*)x_s;
    float gi = bih[j];
#pragma unroll 8
    for (int k = 0; k < 2 * H / 4; ++k) {
      float4 w = wr[k], x = xr[k];
      gi += w.x * x.x + w.y * x.y + w.z * x.z + w.w * x.w;
    }
    const float4* wh = (const float4*)(Whh + (size_t)j * H);
    const float4* hr = (const float4*)h_s;
    float gh = bhh[j];
#pragma unroll 8
    for (int k = 0; k < H / 4; ++k) {
      float4 w = wh[k], hv = hr[k];
      gh += w.x * hv.x + w.y * hv.y + w.z * hv.z + w.w * hv.w;
    }
    gi_s[j] = gi;
    gh_s[j] = gh;
  }
  __syncthreads();
  if (tid < H) {
    float r = 1.f / (1.f + expf(-(gi_s[tid] + gh_s[tid])));
    float z = 1.f / (1.f + expf(-(gi_s[H + tid] + gh_s[H + tid])));
    float n = tanhf(gi_s[2 * H + tid] + r * gh_s[2 * H + tid]);
    float hn = (1.f - z) * n + z * h_s[tid];
    d_out[(size_t)B * V + (size_t)b * H + tid] = hn;
    ws[WS_XCAT2 + (size_t)b * 2 * H + tid] = hn;
    ws[WS_XCAT2 + (size_t)b * 2 * H + H + tid] = cfin;
  }
}

// ---------------- k6: logits = xcat2 @ out_W^T + out_b  (M=64,N=32000,K=512)
// [64][64] LDS tiles, XOR-swizzled (k ^= ((r>>2)&7)<<2) so the 4-spaced row
// reads land on 8 distinct bank groups; float4 LDS reads, k-unroll x4.
__device__ __forceinline__ int swz(int r, int k) {
  return r * 64 + (k ^ (((r >> 2) & 7) << 2));
}
__global__ __launch_bounds__(256) void k6_logits(
    const float* __restrict__ outW, const float* __restrict__ outb,
    const float* __restrict__ ws, float* __restrict__ d_out) {
  __shared__ float As[64 * 64];
  __shared__ float Bs[64 * 64];
  int tid = threadIdx.x;
  int v0 = blockIdx.x * 64;
  int bq = tid & 15, vq = tid >> 4;
  int fa = (bq & 7) << 2;        // swizzle for rows bq*4+i  ((r>>2)&7 == bq&7)
  int fb = (vq & 7) << 2;        // swizzle for rows vq*4+j
  float acc[4][4] = {{0.f}};
  const float* xc = ws + WS_XCAT2;
  for (int kc = 0; kc < 8; ++kc) {
#pragma unroll
    for (int t = 0; t < 16; ++t) {
      int idx = tid + t * 256;   // < 4096
      int k = idx & 63, r = idx >> 6;
      As[swz(r, k)] = xc[(size_t)r * 512 + kc * 64 + k];
      Bs[swz(r, k)] = outW[(size_t)(v0 + r) * 512 + kc * 64 + k];
    }
    __syncthreads();
#pragma unroll
    for (int k = 0; k < 64; k += 4) {
      float4 a[4], bb[4];
#pragma unroll
      for (int i = 0; i < 4; ++i)
        a[i] = *(const float4*)&As[(bq * 4 + i) * 64 + (k ^ fa)];
#pragma unroll
      for (int j = 0; j < 4; ++j)
        bb[j] = *(const float4*)&Bs[(vq * 4 + j) * 64 + (k ^ fb)];
#pragma unroll
      for (int i = 0; i < 4; ++i)
#pragma unroll
        for (int j = 0; j < 4; ++j)
          acc[i][j] += a[i].x * bb[j].x + a[i].y * bb[j].y +
                       a[i].z * bb[j].z + a[i].w * bb[j].w;
    }
    __syncthreads();
  }
#pragma unroll
  for (int i = 0; i < 4; ++i)
#pragma unroll
    for (int j = 0; j < 4; ++j) {
      int bbr = bq * 4 + i;
      int vv = v0 + vq * 4 + j;
      d_out[(size_t)bbr * V + vv] = acc[i][j] + outb[vv];
    }
}

// ---------------- k7k8: in-place log_softmax over V per row
__global__ __launch_bounds__(1024) void k7k8_lsm(float* __restrict__ d_out) {
  int b = blockIdx.x, tid = threadIdx.x;
  __shared__ float red[1024];
  float* row = d_out + (size_t)b * V;
  float m = -INFINITY;
  for (int i = tid; i < V; i += 1024) m = fmaxf(m, row[i]);
  red[tid] = m;
  __syncthreads();
  for (int s = 512; s > 0; s >>= 1) {
    if (tid < s) red[tid] = fmaxf(red[tid], red[tid + s]);
    __syncthreads();
  }
  m = red[0];
  __syncthreads();
  float s0 = 0.f;
  for (int i = tid; i < V; i += 1024) s0 += expf(row[i] - m);
  red[tid] = s0;
  __syncthreads();
  for (int s = 512; s > 0; s >>= 1) {
    if (tid < s) red[tid] += red[tid + s];
    __syncthreads();
  }
  float lsm = m + logf(red[0]);
  for (int i = tid; i < V; i += 1024) row[i] -= lsm;
}

extern "C" void kernel_launch(void* const* d_in, const int* in_sizes, int n_in,
                              void* d_out, int out_size, void* d_ws, size_t ws_size,
                              hipStream_t stream) {
  const int* input = (const int*)d_in[0];
  const float* hidden = (const float*)d_in[1];
  const float* enc = (const float*)d_in[2];
  const float* emb = (const float*)d_in[4];
  const float* attn_W = (const float*)d_in[5];
  const float* flatten = (const float*)d_in[7];
  const float* gru_Wih = (const float*)d_in[8];
  const float* gru_Whh = (const float*)d_in[9];
  const float* gru_bih = (const float*)d_in[10];
  const float* gru_bhh = (const float*)d_in[11];
  const float* out_W = (const float*)d_in[12];
  const float* out_b = (const float*)d_in[13];
  float* out = (float*)d_out;
  float* ws = (float*)d_ws;

  k1_w2<<<1, 1024, 0, stream>>>(attn_W, flatten, ws);
  kA_flash<<<dim3(B, NCH), 256, 0, stream>>>(enc, ws);
  kB_gru<<<B, 768, 0, stream>>>(input, hidden, emb, gru_Wih, gru_Whh,
                                gru_bih, gru_bhh, ws, out);
  k6_logits<<<V / 64, 256, 0, stream>>>(out_W, out_b, ws, out);
  k7k8_lsm<<<B, 1024, 0, stream>>>(out);
}